// Round 8
// baseline (330.980 us; speedup 1.0000x reference)
//
#include <hip/hip_runtime.h>
#include <hip/hip_bf16.h>
#include <math.h>

#define BB 16
#define CC 512
#define HWN 4096
#define KK 4
#define DD 32
#define KD 128

typedef __attribute__((ext_vector_type(8))) short short8;
typedef __attribute__((ext_vector_type(4))) float f32x4;

// ws float offsets
#define WS_Y     0         // [B*C]            8192 f
#define WS_WGT   8192      // [B*K]            64 f
#define WS_BIAS2 8256      // [B*C]            8192 f
#define WS_W1B   16448     // 65536 ushort  = 32768 f
#define WS_W2B   49216     // 65536 ushort  = 32768 f

__device__ inline unsigned short f2bf(float f) {
    unsigned u = __builtin_bit_cast(unsigned, f);
    unsigned r = (u + 0x7FFFu + ((u >> 16) & 1u)) >> 16;
    return (unsigned short)r;
}

// ---------------- kernel 1: y[b,c] = mean_{hw} x[b,c,hw] ----------------
__global__ __launch_bounds__(256) void mean_kernel(const float* __restrict__ x,
                                                   float* __restrict__ y) {
    int wave = threadIdx.x >> 6;
    int lane = threadIdx.x & 63;
    int row  = blockIdx.x * 4 + wave;
    const float4* xr = (const float4*)(x + (size_t)row * HWN);
    float s = 0.f;
    #pragma unroll
    for (int i = 0; i < 16; i++) {
        float4 v = xr[i * 64 + lane];
        s += (v.x + v.y) + (v.z + v.w);
    }
    #pragma unroll
    for (int off = 32; off > 0; off >>= 1)
        s += __shfl_down(s, off, 64);
    if (lane == 0) y[row] = s * (1.0f / HWN);
}

// ---------------- kernel 2: routing softmax -> wgt[b,k] ----------------
__global__ __launch_bounds__(64) void route_kernel(const float* __restrict__ y,
                                                   const float* __restrict__ fc_w,
                                                   const float* __restrict__ fc_b,
                                                   float* __restrict__ wgt) {
    __shared__ float logits[BB][KK];
    int t = threadIdx.x;
    int b = t >> 2, k = t & 3;
    const float4* y4 = (const float4*)(y + b * CC);
    const float4* f4 = (const float4*)(fc_w + k * CC);
    float s = fc_b[k];
    for (int i = 0; i < CC / 4; i++) {
        float4 a = y4[i], w = f4[i];
        s += a.x * w.x + a.y * w.y + a.z * w.z + a.w * w.w;
    }
    logits[b][k] = s;
    __syncthreads();
    if (k == 0) {
        float m = logits[b][0];
        #pragma unroll
        for (int j = 1; j < KK; j++) m = fmaxf(m, logits[b][j]);
        float e[KK], sum = 0.f;
        #pragma unroll
        for (int j = 0; j < KK; j++) { e[j] = __expf(logits[b][j] - m); sum += e[j]; }
        float inv = 1.f / sum;
        #pragma unroll
        for (int j = 0; j < KK; j++) wgt[b * KK + j] = e[j] * inv;
    }
}

// ---- kernel 3: pack W1/W2t into MFMA-fragment-ordered bf16; bias2 ----
__global__ __launch_bounds__(256) void prep_kernel(const float* __restrict__ w1,
                                                   const float* __restrict__ w2,
                                                   const float* __restrict__ b2,
                                                   const float* __restrict__ wgt,
                                                   unsigned short* __restrict__ w1b,
                                                   unsigned short* __restrict__ w2b,
                                                   float* __restrict__ bias2) {
    int tid = blockIdx.x * 256 + threadIdx.x;
    int n   = gridDim.x * 256;
    for (int idx = tid; idx < CC * KD; idx += n) {
        int f = idx >> 9, rem = idx & 511;
        int l = rem >> 3, i = rem & 7;
        int ks = f >> 3, m = f & 7;
        int kd = m * 16 + (l & 15);
        int c  = ks * 32 + (l >> 4) * 8 + i;
        w1b[idx] = f2bf(w1[kd * CC + c]);            // w1 is [KD][C]
    }
    for (int idx = tid; idx < CC * KD; idx += n) {
        int f = idx >> 9, rem = idx & 511;
        int l = rem >> 3, i = rem & 7;
        int mc = f >> 2, kk = f & 3;
        int c = mc * 16 + (l & 15);
        int d = (l >> 4) * 8 + i;
        w2b[idx] = f2bf(w2[(kk * CC + c) * DD + d]); // w2 is [K][C][D]
    }
    for (int idx = tid; idx < BB * CC; idx += n) {
        int bb = idx >> 9, c = idx & 511;
        float s = 0.f;
        #pragma unroll
        for (int k = 0; k < KK; k++) s += wgt[bb * KK + k] * b2[k * CC + c];
        bias2[idx] = s;
    }
}

// -------- kernel 4: wave-independent fused MLP (no LDS, no barriers) --------
// 1 wave = 1 batch x 16-pixel tile, full K. 4096 waves = 1024 blocks x 4.
// GEMM1 (16 ks x 8 m MFMA) -> relu/bias/wgt in regs -> intra-wave shfl
// exchange (C/D frag -> B frag) -> GEMM2 (32 mblk x 4 kk) -> sigmoid*x.
__global__ __launch_bounds__(256, 4) void main_kernel(const float* __restrict__ x,
                                                      const unsigned short* __restrict__ w1b,
                                                      const float* __restrict__ b1,
                                                      const unsigned short* __restrict__ w2b,
                                                      const float* __restrict__ wgt,
                                                      const float* __restrict__ bias2,
                                                      float* __restrict__ out) {
    const int tid = threadIdx.x;
    const int wv  = tid >> 6;
    const int l   = tid & 63;
    const int l15 = l & 15, lg = l >> 4;
    const int job = blockIdx.x * 4 + wv;         // 4096 jobs
    const int b   = job >> 8;                    // 256 pixel-tiles per batch
    const int px  = ((job & 255) << 4) + l15;

    const float* xb = x + (size_t)b * CC * HWN + px;
    const short8* w1f = (const short8*)w1b;
    const short8* w2f = (const short8*)w2b;

    // ===== GEMM1: full K, depth-8 prefetch =====
    f32x4 acc1[8];
    #pragma unroll
    for (int m = 0; m < 8; m++) acc1[m] = (f32x4)0.f;

    float xv[8];
    #pragma unroll
    for (int i = 0; i < 8; i++) xv[i] = xb[(size_t)(lg * 8 + i) * HWN];

    #pragma unroll
    for (int ks = 0; ks < 16; ks++) {
        short8 bf;
        #pragma unroll
        for (int i = 0; i < 8; i++) bf[i] = (short)f2bf(xv[i]);
        if (ks < 15) {
            const float* xn = xb + (size_t)((ks + 1) * 32 + lg * 8) * HWN;
            #pragma unroll
            for (int i = 0; i < 8; i++) xv[i] = xn[(size_t)i * HWN];
        }
        #pragma unroll
        for (int m = 0; m < 8; m++) {
            short8 af = w1f[(ks * 8 + m) * 64 + l];
            acc1[m] = __builtin_amdgcn_mfma_f32_16x16x32_bf16(af, bf, acc1[m], 0, 0, 0);
        }
    }

    // ===== relu + bias + routing weight; pack bf16 pairs =====
    // thread holds hid[kd = m*16 + lg*4 + r][px = l15]
    unsigned hp[16];
    #pragma unroll
    for (int m = 0; m < 8; m++) {
        f32x4 bv = *(const f32x4*)(b1 + m * 16 + lg * 4);
        float wk = wgt[b * KK + (m >> 1)];
        unsigned short h[4];
        #pragma unroll
        for (int r = 0; r < 4; r++)
            h[r] = f2bf(fmaxf(acc1[m][r] + bv[r], 0.f) * wk);
        hp[m * 2 + 0] = (unsigned)h[0] | ((unsigned)h[1] << 16);
        hp[m * 2 + 1] = (unsigned)h[2] | ((unsigned)h[3] << 16);
    }

    // ===== intra-wave exchange: C/D layout -> GEMM2 B-frag layout =====
    // target word w of frag kk = hp[2*(2kk+(lg>>1)) + (w&1)] from lane
    // l15 + 16*((lg&1)*2 + (w>>1)).
    const int src0 = l15 + 16 * ((lg & 1) * 2 + 0);
    const int src1 = l15 + 16 * ((lg & 1) * 2 + 1);
    const bool hi = ((lg >> 1) & 1) != 0;
    unsigned bw[4][4];
    #pragma unroll
    for (int m = 0; m < 8; m++) {
        const bool take = (((m & 1) != 0) == hi);
        #pragma unroll
        for (int rp = 0; rp < 2; rp++) {
            int v0 = __shfl((int)hp[m * 2 + rp], src0, 64);
            int v1 = __shfl((int)hp[m * 2 + rp], src1, 64);
            if (take) { bw[m >> 1][rp] = (unsigned)v0; bw[m >> 1][rp + 2] = (unsigned)v1; }
        }
    }
    short8 breg[4];
    #pragma unroll
    for (int kk = 0; kk < 4; kk++) {
        uint4 u; u.x = bw[kk][0]; u.y = bw[kk][1]; u.z = bw[kk][2]; u.w = bw[kk][3];
        breg[kk] = __builtin_bit_cast(short8, u);
    }

    // ===== GEMM2 over all 512 channels + sigmoid gate + store =====
    const float* bb2 = bias2 + b * CC;
    #pragma unroll 4
    for (int mblk = 0; mblk < 32; mblk++) {
        f32x4 acc = (f32x4)0.f;
        #pragma unroll
        for (int kk = 0; kk < 4; kk++) {
            short8 af = w2f[(mblk * 4 + kk) * 64 + l];
            acc = __builtin_amdgcn_mfma_f32_16x16x32_bf16(af, breg[kk], acc, 0, 0, 0);
        }
        const int cb = mblk * 16 + lg * 4;
        f32x4 b2v = *(const f32x4*)(bb2 + cb);
        #pragma unroll
        for (int r = 0; r < 4; r++) {
            size_t off = ((size_t)b * CC + cb + r) * HWN + px;
            float s = acc[r] + b2v[r];
            float attn = __builtin_amdgcn_rcpf(1.f + __expf(-s));
            __builtin_nontemporal_store(x[off] * attn, &out[off]);
        }
    }
}

extern "C" void kernel_launch(void* const* d_in, const int* in_sizes, int n_in,
                              void* d_out, int out_size, void* d_ws, size_t ws_size,
                              hipStream_t stream) {
    const float* x    = (const float*)d_in[0];
    const float* fc_w = (const float*)d_in[1];
    const float* fc_b = (const float*)d_in[2];
    const float* w1   = (const float*)d_in[3];
    const float* b1   = (const float*)d_in[4];
    const float* w2   = (const float*)d_in[5];
    const float* b2   = (const float*)d_in[6];
    float* out = (float*)d_out;
    float* ws  = (float*)d_ws;

    float* y     = ws + WS_Y;
    float* wgt   = ws + WS_WGT;
    float* bias2 = ws + WS_BIAS2;
    unsigned short* w1b = (unsigned short*)(ws + WS_W1B);
    unsigned short* w2b = (unsigned short*)(ws + WS_W2B);

    mean_kernel <<<dim3(BB * CC / 4), dim3(256), 0, stream>>>(x, y);
    route_kernel<<<dim3(1),           dim3(64),  0, stream>>>(y, fc_w, fc_b, wgt);
    prep_kernel <<<dim3(128),         dim3(256), 0, stream>>>(w1, w2, b2, wgt, w1b, w2b, bias2);
    main_kernel <<<dim3(4096 / 4),    dim3(256), 0, stream>>>(x, w1b, b1, w2b, wgt, bias2, out);
}